// Round 1
// baseline (525.387 us; speedup 1.0000x reference)
//
#include <hip/hip_runtime.h>

// Depth-to-space (CRD / pixel-shuffle), k=3, fp32.
// in:  (B=32, C=9, H=512, W=512)   out: (B=32, 1, 1536, 1536)
// out[b, 0, i*3+r, j*3+s] = in[b, r*3+s, i, j]
//
// R1: non-temporal loads/stores. Working set (302MB in + 302MB out) exceeds
// the 256MiB L3 and has zero reuse — every cache allocation is pure thrash.
// 'nt' modifier streams through L2/MALL without allocating (same regime the
// 6.4 TB/s fillBuffer runs in). Access pattern unchanged from the 483µs
// baseline (kernel-only ~107µs inferred, 90% of 6.3 TB/s achievable).

namespace {
constexpr int B = 32;
constexpr int K = 3;
constexpr int H = 512;
constexpr int W = 512;
constexpr int HW = H * W;          // 262144 floats per plane
constexpr int OW = K * W;          // 1536
constexpr int JBLK = W / 4;        // 128 float4-chunks per input row
// one thread per (b, r, i, jblk): 32 * 3 * 512 * 128 = 6,291,456 threads
constexpr int TOTAL_THREADS = B * K * H * JBLK;

typedef float v4f __attribute__((ext_vector_type(4)));  // nontemporal builtins need a real vector type
}

__global__ __launch_bounds__(256) void d2s_k3_kernel(
    const float* __restrict__ in, float* __restrict__ out) {
    int t = blockIdx.x * blockDim.x + threadIdx.x;

    int jblk = t & (JBLK - 1);     // fastest: keeps wave contiguous in j
    int rest = t >> 7;             // i + H*(r + 3*b)
    int i    = rest & (H - 1);
    int rb   = rest >> 9;          // r + 3*b, in [0, 96)
    int b    = rb / 3;             // compiler magic-mul
    int r    = rb - 3 * b;

    // Input: three planes c = 3r+0, 3r+1, 3r+2, same (i, 4*jblk).
    const v4f* p =
        reinterpret_cast<const v4f*>(in + ((b * 9 + r * 3) * HW + i * W)) + jblk;
    v4f a0 = __builtin_nontemporal_load(p);
    v4f a1 = __builtin_nontemporal_load(p + (HW / 4));
    v4f a2 = __builtin_nontemporal_load(p + 2 * (HW / 4));

    // Interleave (j-major, s-minor): out[3j+s] = plane_s[j]
    v4f o0 = { a0[0], a1[0], a2[0], a0[1] };
    v4f o1 = { a1[1], a2[1], a0[2], a1[2] };
    v4f o2 = { a2[2], a0[3], a1[3], a2[3] };

    // Output row (i*3 + r), cols [jblk*12, jblk*12+12)
    v4f* q = reinterpret_cast<v4f*>(
        out + (b * (K * H * OW) + (i * 3 + r) * OW)) + jblk * 3;
    __builtin_nontemporal_store(o0, q + 0);
    __builtin_nontemporal_store(o1, q + 1);
    __builtin_nontemporal_store(o2, q + 2);
}

extern "C" void kernel_launch(void* const* d_in, const int* in_sizes, int n_in,
                              void* d_out, int out_size, void* d_ws, size_t ws_size,
                              hipStream_t stream) {
    const float* in = (const float*)d_in[0];
    float* out = (float*)d_out;
    // d_in[1] is kernel_size (=3), shapes are fixed by the bench — hardcoded.
    constexpr int block = 256;
    constexpr int grid = TOTAL_THREADS / block;  // 24576
    d2s_k3_kernel<<<grid, block, 0, stream>>>(in, out);
}

// Round 2
// 481.028 us; speedup vs baseline: 1.0922x; 1.0922x over previous
//
#include <hip/hip_runtime.h>

// Depth-to-space (CRD / pixel-shuffle), k=3, fp32.
// in:  (B=32, C=9, H=512, W=512)   out: (B=32, 1, 1536, 1536)
// out[b, 0, i*3+r, j*3+s] = in[b, r*3+s, i, j]
//
// R2: revert R1's nt hints (store-side nt broke L2 write-combining, +38µs).
// New: wave-level LDS store-transpose. Baseline's 3 store instructions each
// wrote 16B/lane at 48B stride (48 partial lines per instr). Stage the wave's
// 192 output float4-chunks in LDS in output order, read back lane-contiguous:
// every global store instruction is now a full 1KiB contiguous burst.
// LDS slots indexed by output chunk g: write slot 3*lane+n, read slot n*64+lane.
// Both phases are conflict-free under contiguous-8-lane b128 serialization
// ((n+3k) mod 8 is a bijection over k since gcd(3,8)=1).

namespace {
constexpr int B = 32;
constexpr int K = 3;
constexpr int H = 512;
constexpr int W = 512;
constexpr int HW = H * W;          // 262144 floats per plane
constexpr int OW = K * W;          // 1536
constexpr int JBLK = W / 4;        // 128 float4-chunks per input row
// one thread per (b, r, i, jblk): 32 * 3 * 512 * 128 = 6,291,456 threads
constexpr int TOTAL_THREADS = B * K * H * JBLK;

typedef float v4f __attribute__((ext_vector_type(4)));
}

__global__ __launch_bounds__(256) void d2s_k3_kernel(
    const float* __restrict__ in, float* __restrict__ out) {
    // 4 waves/block, wave-private 192-chunk (3KiB) regions. 12KiB/block total.
    __shared__ v4f lds[4 * 192];

    int t    = blockIdx.x * blockDim.x + threadIdx.x;
    int lane = threadIdx.x & 63;
    v4f* wlds = lds + (threadIdx.x >> 6) * 192;

    int jblk = t & (JBLK - 1);     // fastest: wave spans 64 consecutive jblk
    int rest = t >> 7;             // i + H*(r + 3*b)  (uniform per wave-pair)
    int i    = rest & (H - 1);
    int rb   = rest >> 9;          // r + 3*b, in [0, 96)
    int b    = rb / 3;             // compiler magic-mul
    int r    = rb - 3 * b;

    // Input: three planes c = 3r+0, 3r+1, 3r+2, same (i, 4*jblk).
    const v4f* p =
        reinterpret_cast<const v4f*>(in + ((b * 9 + r * 3) * HW + i * W)) + jblk;
    v4f a0 = p[0];
    v4f a1 = p[HW / 4];
    v4f a2 = p[2 * (HW / 4)];

    // Interleave (j-major, s-minor): out[3j+s] = plane_s[j]
    v4f o0 = { a0[0], a1[0], a2[0], a0[1] };
    v4f o1 = { a1[1], a2[1], a0[2], a1[2] };
    v4f o2 = { a2[2], a0[3], a1[3], a2[3] };

    // Stage in output-chunk order: chunk g = 3*lane + n.
    wlds[3 * lane + 0] = o0;
    wlds[3 * lane + 1] = o1;
    wlds[3 * lane + 2] = o2;

    __syncthreads();   // orders wave-private LDS write->read; blocks cheap, once

    // Read back so store instruction n covers chunks [n*64, n*64+64).
    v4f s0 = wlds[lane];
    v4f s1 = wlds[64 + lane];
    v4f s2 = wlds[128 + lane];

    // Wave's contiguous 3KiB output window: row (i*3+r), chunk base jblk0*3.
    int jblk0 = jblk & ~63;
    v4f* q = reinterpret_cast<v4f*>(
        out + (b * (K * H * OW) + (i * 3 + r) * OW)) + jblk0 * 3;
    q[lane]       = s0;
    q[64  + lane] = s1;
    q[128 + lane] = s2;
}

extern "C" void kernel_launch(void* const* d_in, const int* in_sizes, int n_in,
                              void* d_out, int out_size, void* d_ws, size_t ws_size,
                              hipStream_t stream) {
    const float* in = (const float*)d_in[0];
    float* out = (float*)d_out;
    // d_in[1] is kernel_size (=3), shapes are fixed by the bench — hardcoded.
    constexpr int block = 256;
    constexpr int grid = TOTAL_THREADS / block;  // 24576
    d2s_k3_kernel<<<grid, block, 0, stream>>>(in, out);
}